// Round 1
// baseline (1055.213 us; speedup 1.0000x reference)
//
#include <hip/hip_runtime.h>
#include <hip/hip_bf16.h>

#define Bb 2
#define Hh 16
#define Ll 2048
#define Dd 64
#define OUT_ELEMS (Bb*Hh*Ll*Dd)

typedef __attribute__((ext_vector_type(8))) short bf16x8;
typedef __attribute__((ext_vector_type(4))) float f32x4;

__device__ __forceinline__ unsigned short f2bf(float f) {
    union { float f; unsigned int u; } a; a.f = f;
    unsigned int r = a.u + 0x7FFFu + ((a.u >> 16) & 1u);
    return (unsigned short)(r >> 16);
}

// swizzled LDS byte offset: rows are 128B (64 bf16); XOR row bits into the
// 16B-block index to kill ds_read_b128 bank conflicts (G4 / m214 pattern)
__device__ __forceinline__ int swz(int row, int colByte) {
    return row * 128 + (colByte ^ ((row & 7) << 4));
}

__global__ __launch_bounds__(256)
void attn_fused(const float* __restrict__ Q, const float* __restrict__ K,
                const float* __restrict__ V, const int* __restrict__ M,
                const float* __restrict__ Bi, float* __restrict__ out)
{
    __shared__ char Qs[64 * 128];
    __shared__ char Ks[64 * 128];
    __shared__ char VTs[64 * 128];
    __shared__ char Ps[64 * 128];

    const int bid = blockIdx.x;
    const int qt = bid & 31;          // q-tile fastest
    const int h  = (bid >> 5) & 15;
    const int b  = bid >> 9;
    const int q0 = qt * 64;

    const int tid  = threadIdx.x;
    const int w    = tid >> 6;        // wave 0..3, owns q-rows [16w,16w+16)
    const int lane = tid & 63;
    const int g    = lane >> 4;       // 4-lane-group (k/row sub-block)
    const int c16  = lane & 15;

    const float* Qp = Q  + ((size_t)(b * Hh + h) * Ll + q0) * Dd;
    const float* Kp = K  + (size_t)(b * Hh + h) * Ll * Dd;
    const float* Vp = V  + (size_t)(b * Hh + h) * Ll * Dd;
    const int*   Mp = M  + (size_t)b * Ll * Ll + (size_t)q0 * Ll;
    const float* Bp = Bi + (size_t)h * Ll * Ll + (size_t)q0 * Ll;
    float* Op = out + ((size_t)(b * Hh + h) * Ll + q0) * Dd;
    float* Sp = out + OUT_ELEMS + ((size_t)(b * Hh + h) * Ll + q0) * Ll;

    // ---- load Q tile (64 rows x 64 d) -> Qs (bf16, swizzled) ----
    {
        int r0 = tid >> 4, d0 = (tid & 15) * 4;
#pragma unroll
        for (int rep = 0; rep < 4; ++rep) {
            int row = r0 + rep * 16;
            float4 v = *(const float4*)(Qp + row * Dd + d0);
            ushort4 u = { f2bf(v.x), f2bf(v.y), f2bf(v.z), f2bf(v.w) };
            *(ushort4*)(Qs + swz(row, d0 * 2)) = u;
        }
    }

    auto loadK = [&](int k0) {
        int r0 = tid >> 4, d0 = (tid & 15) * 4;
#pragma unroll
        for (int rep = 0; rep < 4; ++rep) {
            int row = r0 + rep * 16;
            float4 v = *(const float4*)(Kp + (size_t)(k0 + row) * Dd + d0);
            ushort4 u = { f2bf(v.x), f2bf(v.y), f2bf(v.z), f2bf(v.w) };
            *(ushort4*)(Ks + swz(row, d0 * 2)) = u;
        }
    };

    // S-tile MFMA: S[16w+4g+r][k0+16ct+c16] in sacc[ct][r]
    auto mfmaS = [&](f32x4 (&sacc)[4]) {
#pragma unroll
        for (int kk = 0; kk < 2; ++kk) {
            bf16x8 af = *(const bf16x8*)(Qs + swz(w * 16 + c16, kk * 64 + g * 16));
#pragma unroll
            for (int ct = 0; ct < 4; ++ct) {
                bf16x8 bf = *(const bf16x8*)(Ks + swz(ct * 16 + c16, kk * 64 + g * 16));
                sacc[ct] = __builtin_amdgcn_mfma_f32_16x16x32_bf16(af, bf, sacc[ct], 0, 0, 0);
            }
        }
    };

    // ================= sweep 1: row sums of exp(S) =================
    float rs[4] = {0.f, 0.f, 0.f, 0.f};
    for (int k0 = 0; k0 < Ll; k0 += 64) {
        __syncthreads();
        loadK(k0);
        __syncthreads();
        f32x4 sacc[4] = {{0,0,0,0},{0,0,0,0},{0,0,0,0},{0,0,0,0}};
        mfmaS(sacc);
#pragma unroll
        for (int ct = 0; ct < 4; ++ct) {
            int kc = k0 + ct * 16 + c16;
#pragma unroll
            for (int r = 0; r < 4; ++r) {
                int qr = w * 16 + g * 4 + r;
                int idx = qr * Ll + kc;
                float s = sacc[ct][r] * 0.125f;
                s = (Mp[idx] == 0 ? -10000.0f : s) + Bp[idx];
                rs[r] += __expf(s);
            }
        }
    }
#pragma unroll
    for (int off = 1; off < 16; off <<= 1)
#pragma unroll
        for (int r = 0; r < 4; ++r)
            rs[r] += __shfl_xor(rs[r], off);
    float inv[4];
#pragma unroll
    for (int r = 0; r < 4; ++r) inv[r] = 1.0f / rs[r];

    // ====== sweep 2: recompute S, write P fp32, accumulate O=P·V ======
    f32x4 oacc[4] = {{0,0,0,0},{0,0,0,0},{0,0,0,0},{0,0,0,0}};
    for (int k0 = 0; k0 < Ll; k0 += 64) {
        __syncthreads();
        loadK(k0);
        { // V tile transposed: VTs[d][k], coalesced global reads per d
            int d = lane;
#pragma unroll
            for (int r = 0; r < 4; ++r) {
                int kb = w * 16 + r * 4;
                float f0 = Vp[(size_t)(k0 + kb + 0) * Dd + d];
                float f1 = Vp[(size_t)(k0 + kb + 1) * Dd + d];
                float f2 = Vp[(size_t)(k0 + kb + 2) * Dd + d];
                float f3 = Vp[(size_t)(k0 + kb + 3) * Dd + d];
                ushort4 u = { f2bf(f0), f2bf(f1), f2bf(f2), f2bf(f3) };
                *(ushort4*)(VTs + swz(d, kb * 2)) = u;
            }
        }
        __syncthreads();
        f32x4 sacc[4] = {{0,0,0,0},{0,0,0,0},{0,0,0,0},{0,0,0,0}};
        mfmaS(sacc);
#pragma unroll
        for (int ct = 0; ct < 4; ++ct) {
            int kc = k0 + ct * 16 + c16;
#pragma unroll
            for (int r = 0; r < 4; ++r) {
                int qr = w * 16 + g * 4 + r;
                int idx = qr * Ll + kc;
                float s = sacc[ct][r] * 0.125f;
                s = (Mp[idx] == 0 ? -10000.0f : s) + Bp[idx];
                float p = __expf(s) * inv[r];
                Sp[(size_t)qr * Ll + kc] = p;                       // fp32 P out
                *(unsigned short*)(Ps + swz(qr, (ct * 16 + c16) * 2)) = f2bf(p);
            }
        }
        __syncthreads();
#pragma unroll
        for (int kk = 0; kk < 2; ++kk) {
            bf16x8 pf = *(const bf16x8*)(Ps + swz(w * 16 + c16, kk * 64 + g * 16));
#pragma unroll
            for (int dt = 0; dt < 4; ++dt) {
                bf16x8 vf = *(const bf16x8*)(VTs + swz(dt * 16 + c16, kk * 64 + g * 16));
                oacc[dt] = __builtin_amdgcn_mfma_f32_16x16x32_bf16(pf, vf, oacc[dt], 0, 0, 0);
            }
        }
    }

    // ---- write O (already normalized) ----
#pragma unroll
    for (int dt = 0; dt < 4; ++dt)
#pragma unroll
        for (int r = 0; r < 4; ++r)
            Op[(w * 16 + g * 4 + r) * Dd + dt * 16 + c16] = oacc[dt][r];
}

extern "C" void kernel_launch(void* const* d_in, const int* in_sizes, int n_in,
                              void* d_out, int out_size, void* d_ws, size_t ws_size,
                              hipStream_t stream) {
    const float* Q  = (const float*)d_in[0];
    const float* K  = (const float*)d_in[1];
    const float* V  = (const float*)d_in[2];
    const int*   M  = (const int*)d_in[3];
    const float* Bi = (const float*)d_in[4];
    float* out = (float*)d_out;

    dim3 grid(Bb * Hh * (Ll / 64));   // 1024 blocks: (b,h,qtile), qtile fastest
    dim3 block(256);
    attn_fused<<<grid, block, 0, stream>>>(Q, K, V, M, Bi, out);
}

// Round 2
// 605.133 us; speedup vs baseline: 1.7438x; 1.7438x over previous
//
#include <hip/hip_runtime.h>
#include <hip/hip_bf16.h>

#define Bb 2
#define Hh 16
#define Ll 2048
#define Dd 64
#define OUT_ELEMS (Bb*Hh*Ll*Dd)

typedef __attribute__((ext_vector_type(8))) short bf16x8;
typedef __attribute__((ext_vector_type(4))) float f32x4;
typedef __attribute__((ext_vector_type(4))) int i32x4;

__device__ __forceinline__ unsigned short f2bf(float f) {
    union { float f; unsigned int u; } a; a.f = f;
    unsigned int r = a.u + 0x7FFFu + ((a.u >> 16) & 1u);
    return (unsigned short)(r >> 16);
}

// swizzled LDS byte offset: rows are 128B (64 bf16); XOR row bits into the
// 16B-block index to kill ds_read_b128 bank conflicts (G4 / m214 pattern)
__device__ __forceinline__ int swz(int row, int colByte) {
    return row * 128 + (colByte ^ ((row & 7) << 4));
}

__global__ __launch_bounds__(256)
void attn_fused(const float* __restrict__ Q, const float* __restrict__ K,
                const float* __restrict__ V, const int* __restrict__ M,
                const float* __restrict__ Bi, float* __restrict__ out)
{
    __shared__ char Ks[64 * 128];
    __shared__ char VTs[64 * 128];
    __shared__ char Ps[64 * 128];

    const int bid = blockIdx.x;
    const int b  = bid & 1;           // b innermost: bias-slice users adjacent
    const int qt = (bid >> 1) & 31;
    const int h  = bid >> 6;
    const int q0 = qt * 64;

    const int tid  = threadIdx.x;
    const int w    = tid >> 6;        // wave 0..3, owns q-rows [16w,16w+16)
    const int lane = tid & 63;
    const int g    = lane >> 4;
    const int c16  = lane & 15;
    const int qr   = w * 16 + c16;    // this lane's q row (tile-local), fixed

    const float* Qp = Q  + ((size_t)(b * Hh + h) * Ll + q0) * Dd;
    const float* Kp = K  + (size_t)(b * Hh + h) * Ll * Dd;
    const float* Vp = V  + (size_t)(b * Hh + h) * Ll * Dd;
    const int*   Mp = M  + (size_t)b * Ll * Ll + (size_t)q0 * Ll;
    const float* Bp = Bi + (size_t)h * Ll * Ll + (size_t)q0 * Ll;
    float* Op = out + ((size_t)(b * Hh + h) * Ll + q0) * Dd;
    float* Sp = out + OUT_ELEMS + ((size_t)(b * Hh + h) * Ll + q0) * Ll;

    const size_t ro = (size_t)qr * Ll;   // lane's mask/bias/P row offset

    // ---- Q fragments straight into registers (B operand of S^T mfma) ----
    bf16x8 qf[2];
    {
        const float* qrow = Qp + qr * Dd;
#pragma unroll
        for (int kk = 0; kk < 2; ++kk) {
            f32x4 a = *(const f32x4*)(qrow + kk * 32 + g * 8);
            f32x4 c = *(const f32x4*)(qrow + kk * 32 + g * 8 + 4);
            bf16x8 q8;
            q8[0] = (short)f2bf(a[0]); q8[1] = (short)f2bf(a[1]);
            q8[2] = (short)f2bf(a[2]); q8[3] = (short)f2bf(a[3]);
            q8[4] = (short)f2bf(c[0]); q8[5] = (short)f2bf(c[1]);
            q8[6] = (short)f2bf(c[2]); q8[7] = (short)f2bf(c[3]);
            qf[kk] = q8;
        }
    }

    auto loadK = [&](int k0) {
        int r0 = tid >> 4, d0 = (tid & 15) * 4;
#pragma unroll
        for (int rep = 0; rep < 4; ++rep) {
            int row = r0 + rep * 16;
            float4 v = *(const float4*)(Kp + (size_t)(k0 + row) * Dd + d0);
            ushort4 u = { f2bf(v.x), f2bf(v.y), f2bf(v.z), f2bf(v.w) };
            *(ushort4*)(Ks + swz(row, d0 * 2)) = u;
        }
    };

    auto loadVT = [&](int k0) {       // V transposed: VTs[d][k]
        int d = lane;
#pragma unroll
        for (int r = 0; r < 4; ++r) {
            int kb = w * 16 + r * 4;
            float f0 = Vp[(size_t)(k0 + kb + 0) * Dd + d];
            float f1 = Vp[(size_t)(k0 + kb + 1) * Dd + d];
            float f2 = Vp[(size_t)(k0 + kb + 2) * Dd + d];
            float f3 = Vp[(size_t)(k0 + kb + 3) * Dd + d];
            ushort4 u = { f2bf(f0), f2bf(f1), f2bf(f2), f2bf(f3) };
            *(ushort4*)(VTs + swz(d, kb * 2)) = u;
        }
    };

    // S^T tile: sacc[ct][r] = S[k0 + ct*16 + g*4 + r][q0 + qr]
    auto mfmaST = [&](f32x4 (&sacc)[4]) {
#pragma unroll
        for (int kk = 0; kk < 2; ++kk) {
#pragma unroll
            for (int ct = 0; ct < 4; ++ct) {
                bf16x8 af = *(const bf16x8*)(Ks + swz(ct * 16 + c16, kk * 64 + g * 16));
                sacc[ct] = __builtin_amdgcn_mfma_f32_16x16x32_bf16(af, qf[kk], sacc[ct], 0, 0, 0);
            }
        }
    };

    // ================= sweep 1: per-q-row sums of exp(S) =================
    float rsv[4] = {0.f, 0.f, 0.f, 0.f};
    for (int k0 = 0; k0 < Ll; k0 += 64) {
        __syncthreads();
        i32x4 m4[4];
        f32x4 b4[4];
#pragma unroll
        for (int ct = 0; ct < 4; ++ct) {
            m4[ct] = *(const i32x4*)(Mp + ro + k0 + ct * 16 + g * 4);
            b4[ct] = *(const f32x4*)(Bp + ro + k0 + ct * 16 + g * 4);
        }
        loadK(k0);
        __syncthreads();
        f32x4 sacc[4] = {{0,0,0,0},{0,0,0,0},{0,0,0,0},{0,0,0,0}};
        mfmaST(sacc);
#pragma unroll
        for (int ct = 0; ct < 4; ++ct)
#pragma unroll
            for (int r = 0; r < 4; ++r) {
                float s = sacc[ct][r] * 0.125f;
                s = (m4[ct][r] == 0 ? -10000.0f : s) + b4[ct][r];
                rsv[ct] += __expf(s);
            }
    }
    float rs = (rsv[0] + rsv[1]) + (rsv[2] + rsv[3]);
    rs += __shfl_xor(rs, 16);
    rs += __shfl_xor(rs, 32);
    const float inv = 1.0f / rs;

    // ====== sweep 2: recompute S^T, write P fp32 (vec4, NT), O = P·V ======
    f32x4 oacc[4] = {{0,0,0,0},{0,0,0,0},{0,0,0,0},{0,0,0,0}};
    for (int k0 = 0; k0 < Ll; k0 += 64) {
        __syncthreads();
        i32x4 m4[4];
        f32x4 b4[4];
#pragma unroll
        for (int ct = 0; ct < 4; ++ct) {
            m4[ct] = *(const i32x4*)(Mp + ro + k0 + ct * 16 + g * 4);
            b4[ct] = *(const f32x4*)(Bp + ro + k0 + ct * 16 + g * 4);
        }
        loadK(k0);
        loadVT(k0);
        __syncthreads();
        f32x4 sacc[4] = {{0,0,0,0},{0,0,0,0},{0,0,0,0},{0,0,0,0}};
        mfmaST(sacc);
#pragma unroll
        for (int ct = 0; ct < 4; ++ct) {
            f32x4 p;
#pragma unroll
            for (int r = 0; r < 4; ++r) {
                float s = sacc[ct][r] * 0.125f;
                s = (m4[ct][r] == 0 ? -10000.0f : s) + b4[ct][r];
                p[r] = __expf(s) * inv;
            }
            __builtin_nontemporal_store(p, (f32x4*)(Sp + ro + k0 + ct * 16 + g * 4));
            ushort4 u = { (unsigned short)f2bf(p[0]), (unsigned short)f2bf(p[1]),
                          (unsigned short)f2bf(p[2]), (unsigned short)f2bf(p[3]) };
            *(ushort4*)(Ps + swz(qr, ct * 32 + g * 8)) = u;   // own-wave rows only
        }
        // PV: Ps rows are wave-private → no barrier needed before reading
#pragma unroll
        for (int kk = 0; kk < 2; ++kk) {
            bf16x8 pf = *(const bf16x8*)(Ps + swz(qr, kk * 64 + g * 16));
#pragma unroll
            for (int dt = 0; dt < 4; ++dt) {
                bf16x8 vf = *(const bf16x8*)(VTs + swz(dt * 16 + c16, kk * 64 + g * 16));
                oacc[dt] = __builtin_amdgcn_mfma_f32_16x16x32_bf16(pf, vf, oacc[dt], 0, 0, 0);
            }
        }
    }

    // ---- write O (already normalized; C rows = q = w*16 + g*4 + r) ----
#pragma unroll
    for (int dt = 0; dt < 4; ++dt)
#pragma unroll
        for (int r = 0; r < 4; ++r)
            Op[(w * 16 + g * 4 + r) * Dd + dt * 16 + c16] = oacc[dt][r];
}

extern "C" void kernel_launch(void* const* d_in, const int* in_sizes, int n_in,
                              void* d_out, int out_size, void* d_ws, size_t ws_size,
                              hipStream_t stream) {
    const float* Q  = (const float*)d_in[0];
    const float* K  = (const float*)d_in[1];
    const float* V  = (const float*)d_in[2];
    const int*   M  = (const int*)d_in[3];
    const float* Bi = (const float*)d_in[4];
    float* out = (float*)d_out;

    dim3 grid(Bb * Hh * (Ll / 64));   // 1024 blocks: b innermost, then qt, h
    dim3 block(256);
    attn_fused<<<grid, block, 0, stream>>>(Q, K, V, M, Bi, out);
}

// Round 3
// 476.286 us; speedup vs baseline: 2.2155x; 1.2705x over previous
//
#include <hip/hip_runtime.h>
#include <hip/hip_bf16.h>

#define Bb 2
#define Hh 16
#define Ll 2048
#define Dd 64
#define OUT_ELEMS (Bb*Hh*Ll*Dd)
#define NT (Ll/64)

typedef __attribute__((ext_vector_type(8))) short bf16x8;
typedef __attribute__((ext_vector_type(4))) float f32x4;
typedef __attribute__((ext_vector_type(4))) int i32x4;

__device__ __forceinline__ unsigned short f2bf(float f) {
    union { float f; unsigned int u; } a; a.f = f;
    unsigned int r = a.u + 0x7FFFu + ((a.u >> 16) & 1u);
    return (unsigned short)(r >> 16);
}

// swizzled LDS byte offset: rows are 128B (64 bf16); XOR row bits into the
// 16B-block index to kill ds_read_b128 bank conflicts (G4 / m214 pattern)
__device__ __forceinline__ int swz(int row, int colByte) {
    return row * 128 + (colByte ^ ((row & 7) << 4));
}

__global__ __launch_bounds__(256)
void attn_fused(const float* __restrict__ Q, const float* __restrict__ K,
                const float* __restrict__ V, const int* __restrict__ M,
                const float* __restrict__ Bi, float* __restrict__ out)
{
    __shared__ char Ks[64 * 128];
    __shared__ char VTs[64 * 128];
    __shared__ char Ps[64 * 128];

    const int bid = blockIdx.x;
    const int b  = bid & 1;           // b innermost: bias-slice users adjacent
    const int qt = (bid >> 1) & 31;
    const int h  = bid >> 6;
    const int q0 = qt * 64;

    const int tid  = threadIdx.x;
    const int w    = tid >> 6;        // wave 0..3, owns q-rows [16w,16w+16)
    const int lane = tid & 63;
    const int g    = lane >> 4;
    const int c16  = lane & 15;
    const int qr   = w * 16 + c16;    // this lane's q row (tile-local), fixed

    const float* Qp = Q  + ((size_t)(b * Hh + h) * Ll + q0) * Dd;
    const float* Kp = K  + (size_t)(b * Hh + h) * Ll * Dd;
    const float* Vp = V  + (size_t)(b * Hh + h) * Ll * Dd;
    const int*   Mp = M  + (size_t)b * Ll * Ll + (size_t)q0 * Ll;
    const float* Bp = Bi + (size_t)h * Ll * Ll + (size_t)q0 * Ll;
    float* Op = out + ((size_t)(b * Hh + h) * Ll + q0) * Dd;
    float* Sp = out + OUT_ELEMS + ((size_t)(b * Hh + h) * Ll + q0) * Ll;

    const size_t ro = (size_t)qr * Ll;   // lane's mask/bias/P row offset

    // ---- Q fragments straight into registers (B operand of S^T mfma) ----
    bf16x8 qf[2];
    {
        const float* qrow = Qp + qr * Dd;
#pragma unroll
        for (int kk = 0; kk < 2; ++kk) {
            f32x4 a = *(const f32x4*)(qrow + kk * 32 + g * 8);
            f32x4 c = *(const f32x4*)(qrow + kk * 32 + g * 8 + 4);
            bf16x8 q8;
            q8[0] = (short)f2bf(a[0]); q8[1] = (short)f2bf(a[1]);
            q8[2] = (short)f2bf(a[2]); q8[3] = (short)f2bf(a[3]);
            q8[4] = (short)f2bf(c[0]); q8[5] = (short)f2bf(c[1]);
            q8[6] = (short)f2bf(c[2]); q8[7] = (short)f2bf(c[3]);
            qf[kk] = q8;
        }
    }

    // ---- prefetch register sets (1 iteration deep) ----
    float4 kreg[4];     // K tile staging
    float  vreg[16];    // V tile staging (sweep 2 only)
    i32x4  m4[4];       // mask
    f32x4  b4[4];       // bias

    const int r0 = tid >> 4, d0 = (tid & 15) * 4;

    auto issueK = [&](int k0) {
#pragma unroll
        for (int rep = 0; rep < 4; ++rep)
            kreg[rep] = *(const float4*)(Kp + (size_t)(k0 + r0 + rep * 16) * Dd + d0);
    };
    auto writeK = [&]() {
#pragma unroll
        for (int rep = 0; rep < 4; ++rep) {
            int row = r0 + rep * 16;
            ushort4 u = { f2bf(kreg[rep].x), f2bf(kreg[rep].y),
                          f2bf(kreg[rep].z), f2bf(kreg[rep].w) };
            *(ushort4*)(Ks + swz(row, d0 * 2)) = u;
        }
    };
    auto issueV = [&](int k0) {
#pragma unroll
        for (int r = 0; r < 4; ++r)
#pragma unroll
            for (int i = 0; i < 4; ++i)
                vreg[r * 4 + i] = Vp[(size_t)(k0 + w * 16 + r * 4 + i) * Dd + lane];
    };
    auto writeV = [&]() {             // transposed: VTs[d][k]
#pragma unroll
        for (int r = 0; r < 4; ++r) {
            ushort4 u = { f2bf(vreg[r * 4 + 0]), f2bf(vreg[r * 4 + 1]),
                          f2bf(vreg[r * 4 + 2]), f2bf(vreg[r * 4 + 3]) };
            *(ushort4*)(VTs + swz(lane, (w * 16 + r * 4) * 2)) = u;
        }
    };
    auto issueMB = [&](int k0) {
#pragma unroll
        for (int ct = 0; ct < 4; ++ct) {
            m4[ct] = *(const i32x4*)(Mp + ro + k0 + ct * 16 + g * 4);
            b4[ct] = *(const f32x4*)(Bp + ro + k0 + ct * 16 + g * 4);
        }
    };

    // S^T tile: sacc[ct][r] = S[k0 + ct*16 + g*4 + r][q0 + qr]
    auto mfmaST = [&](f32x4 (&sacc)[4]) {
#pragma unroll
        for (int kk = 0; kk < 2; ++kk) {
#pragma unroll
            for (int ct = 0; ct < 4; ++ct) {
                bf16x8 af = *(const bf16x8*)(Ks + swz(ct * 16 + c16, kk * 64 + g * 16));
                sacc[ct] = __builtin_amdgcn_mfma_f32_16x16x32_bf16(af, qf[kk], sacc[ct], 0, 0, 0);
            }
        }
    };

    // ================= sweep 1: per-q-row sums of exp(S) =================
    issueK(0);
    issueMB(0);
    float rsv[4] = {0.f, 0.f, 0.f, 0.f};
    for (int t = 0; t < NT; ++t) {
        __syncthreads();              // readers of Ks (iter t-1) done
        writeK();                     // waits vmcnt on kreg (issued at t-1)
        issueK(((t + 1) & (NT - 1)) * 64);   // wraps: warms sweep 2 at t=NT-1
        __syncthreads();              // Ks ready
        f32x4 sacc[4] = {{0,0,0,0},{0,0,0,0},{0,0,0,0},{0,0,0,0}};
        mfmaST(sacc);
#pragma unroll
        for (int ct = 0; ct < 4; ++ct)
#pragma unroll
            for (int r = 0; r < 4; ++r) {
                float s = sacc[ct][r] * 0.125f;
                s = (m4[ct][r] == 0 ? -10000.0f : s) + b4[ct][r];
                rsv[ct] += __expf(s);
            }
        issueMB(((t + 1) & (NT - 1)) * 64);  // after last use of m4/b4
    }
    float rs = (rsv[0] + rsv[1]) + (rsv[2] + rsv[3]);
    rs += __shfl_xor(rs, 16);
    rs += __shfl_xor(rs, 32);
    const float inv = 1.0f / rs;

    // ====== sweep 2: recompute S^T, write P fp32 (vec4, NT), O = P·V ======
    // kreg + m4/b4 already hold tile 0 (wrapped prefetch from sweep 1)
    issueV(0);
    f32x4 oacc[4] = {{0,0,0,0},{0,0,0,0},{0,0,0,0},{0,0,0,0}};
    for (int t = 0; t < NT; ++t) {
        __syncthreads();              // readers of Ks/VTs (iter t-1) done
        writeK();
        writeV();
        issueK(((t + 1) & (NT - 1)) * 64);
        issueV(((t + 1) & (NT - 1)) * 64);
        __syncthreads();              // LDS ready
        f32x4 sacc[4] = {{0,0,0,0},{0,0,0,0},{0,0,0,0},{0,0,0,0}};
        mfmaST(sacc);
        const int k0 = t * 64;
#pragma unroll
        for (int ct = 0; ct < 4; ++ct) {
            f32x4 p;
#pragma unroll
            for (int r = 0; r < 4; ++r) {
                float s = sacc[ct][r] * 0.125f;
                s = (m4[ct][r] == 0 ? -10000.0f : s) + b4[ct][r];
                p[r] = __expf(s) * inv;
            }
            __builtin_nontemporal_store(p, (f32x4*)(Sp + ro + k0 + ct * 16 + g * 4));
            ushort4 u = { (unsigned short)f2bf(p[0]), (unsigned short)f2bf(p[1]),
                          (unsigned short)f2bf(p[2]), (unsigned short)f2bf(p[3]) };
            *(ushort4*)(Ps + swz(qr, ct * 32 + g * 8)) = u;   // own-wave rows only
        }
        issueMB(((t + 1) & (NT - 1)) * 64);  // after last use of m4/b4
        // PV: Ps rows are wave-private → no barrier needed before reading
#pragma unroll
        for (int kk = 0; kk < 2; ++kk) {
            bf16x8 pf = *(const bf16x8*)(Ps + swz(qr, kk * 64 + g * 16));
#pragma unroll
            for (int dt = 0; dt < 4; ++dt) {
                bf16x8 vf = *(const bf16x8*)(VTs + swz(dt * 16 + c16, kk * 64 + g * 16));
                oacc[dt] = __builtin_amdgcn_mfma_f32_16x16x32_bf16(pf, vf, oacc[dt], 0, 0, 0);
            }
        }
    }

    // ---- write O (already normalized; C rows = q = w*16 + g*4 + r) ----
#pragma unroll
    for (int dt = 0; dt < 4; ++dt)
#pragma unroll
        for (int r = 0; r < 4; ++r)
            Op[(w * 16 + g * 4 + r) * Dd + dt * 16 + c16] = oacc[dt][r];
}

extern "C" void kernel_launch(void* const* d_in, const int* in_sizes, int n_in,
                              void* d_out, int out_size, void* d_ws, size_t ws_size,
                              hipStream_t stream) {
    const float* Q  = (const float*)d_in[0];
    const float* K  = (const float*)d_in[1];
    const float* V  = (const float*)d_in[2];
    const int*   M  = (const int*)d_in[3];
    const float* Bi = (const float*)d_in[4];
    float* out = (float*)d_out;

    dim3 grid(Bb * Hh * (Ll / 64));   // 1024 blocks: b innermost, then qt, h
    dim3 block(256);
    attn_fused<<<grid, block, 0, stream>>>(Q, K, V, M, Bi, out);
}